// Round 1
// baseline (263.522 us; speedup 1.0000x reference)
//
#include <hip/hip_runtime.h>
#include <cmath>

constexpr int D   = 512;
constexpr int NC  = 225;   // number of classes
constexpr int NPC = 224;   // outputs per class

// One block per token. 256 threads.
// Phase 1: thread c (< 225) computes class logit c = dot(x, W1[:,c]) + b1[c].
// Phase 2: thread o (< 224) computes in-class logit o = dot(x, W2[cls,:,o]) + b2[cls,o].
// Both phases: LDS tree reduce for softmax max & sum.
__global__ __launch_bounds__(256) void hsm_kernel(
    const float* __restrict__ x,
    const int*   __restrict__ target,
    const float* __restrict__ W1,
    const float* __restrict__ b1,
    const float* __restrict__ W2,
    const float* __restrict__ b2,
    float*       __restrict__ out)
{
    __shared__ float xs[D];
    __shared__ float red[256];
    __shared__ float sh_p1;

    const int n   = blockIdx.x;
    const int tid = threadIdx.x;

    // Stage x row in LDS (128 x float4 = 512 floats)
    if (tid < 128) {
        reinterpret_cast<float4*>(xs)[tid] =
            reinterpret_cast<const float4*>(x + (size_t)n * D)[tid];
    }
    const int t   = target[n];
    const int cls = t / NPC;
    const int idx = t % NPC;
    __syncthreads();

    // ---------------- phase 1: class softmax ----------------
    float logit = -INFINITY;
    if (tid < NC) {
        float acc = 0.f;
        const float* w = W1 + tid;           // column tid, stride NC
        #pragma unroll 8
        for (int d = 0; d < D; ++d)
            acc = fmaf(xs[d], w[d * NC], acc);
        logit = acc + b1[tid];
    }

    // max reduce over 256 slots
    red[tid] = logit;
    __syncthreads();
    #pragma unroll
    for (int s = 128; s > 0; s >>= 1) {
        if (tid < s) red[tid] = fmaxf(red[tid], red[tid + s]);
        __syncthreads();
    }
    const float m1 = red[0];
    __syncthreads();

    const float e1 = (tid < NC) ? __expf(logit - m1) : 0.f;
    red[tid] = e1;
    __syncthreads();
    #pragma unroll
    for (int s = 128; s > 0; s >>= 1) {
        if (tid < s) red[tid] += red[tid + s];
        __syncthreads();
    }
    const float sum1 = red[0];
    if (tid == cls) sh_p1 = e1 / sum1;       // p(class = cls | x)
    __syncthreads();                          // also guards red[] reuse

    // ---------------- phase 2: in-class softmax ----------------
    float logit2 = -INFINITY;
    if (tid < NPC) {
        float acc = 0.f;
        const float* w = W2 + (size_t)cls * (D * NPC) + tid;  // column tid, stride NPC
        #pragma unroll 8
        for (int d = 0; d < D; ++d)
            acc = fmaf(xs[d], w[d * NPC], acc);
        logit2 = acc + b2[cls * NPC + tid];
    }

    red[tid] = logit2;
    __syncthreads();
    #pragma unroll
    for (int s = 128; s > 0; s >>= 1) {
        if (tid < s) red[tid] = fmaxf(red[tid], red[tid + s]);
        __syncthreads();
    }
    const float m2 = red[0];
    __syncthreads();

    const float e2 = (tid < NPC) ? __expf(logit2 - m2) : 0.f;
    red[tid] = e2;
    __syncthreads();
    #pragma unroll
    for (int s = 128; s > 0; s >>= 1) {
        if (tid < s) red[tid] += red[tid + s];
        __syncthreads();
    }
    const float sum2 = red[0];

    if (tid == idx) out[n] = sh_p1 * (e2 / sum2);
}

extern "C" void kernel_launch(void* const* d_in, const int* in_sizes, int n_in,
                              void* d_out, int out_size, void* d_ws, size_t ws_size,
                              hipStream_t stream) {
    const float* x      = (const float*)d_in[0];
    const int*   target = (const int*)  d_in[1];
    const float* W1     = (const float*)d_in[2];
    const float* b1     = (const float*)d_in[3];
    const float* W2     = (const float*)d_in[4];
    const float* b2     = (const float*)d_in[5];
    float* out = (float*)d_out;

    const int Ntok = in_sizes[1];   // B*L = 4096 tokens
    hsm_kernel<<<Ntok, 256, 0, stream>>>(x, target, W1, b1, W2, b2, out);
}

// Round 2
// 195.912 us; speedup vs baseline: 1.3451x; 1.3451x over previous
//
#include <hip/hip_runtime.h>
#include <cmath>

constexpr int D    = 512;
constexpr int NC   = 225;   // number of classes
constexpr int NPC  = 224;   // outputs per class
constexpr int T1   = 16;    // tokens per phase-1 block
constexpr int T2   = 32;    // tokens per phase-2 chunk

// ws layout (as int*):
//   [0   .. 225]   offsets (226 entries, offsets[225] = ntok)
//   [256 .. 480]   cursor  (225 entries)
//   [512 .. 4607]  order   (ntok entries)
//   [4608.. 8703]  p1      (ntok floats)
constexpr int WS_OFF    = 0;
constexpr int WS_CURSOR = 256;
constexpr int WS_ORDER  = 512;
constexpr int WS_P1     = 512 + 4096;

// ---------------- prep: histogram + exclusive scan ----------------
__global__ __launch_bounds__(256) void k_prep(const int* __restrict__ target,
                                              int* __restrict__ ws, int ntok) {
    __shared__ int h[NC];
    __shared__ int off[NC + 1];
    const int tid = threadIdx.x;
    for (int c = tid; c < NC; c += 256) h[c] = 0;
    __syncthreads();
    for (int n = tid; n < ntok; n += 256) {
        int c = target[n] / NPC;
        atomicAdd(&h[c], 1);
    }
    __syncthreads();
    if (tid == 0) {
        int s = 0;
        for (int c = 0; c < NC; ++c) { off[c] = s; s += h[c]; }
        off[NC] = s;
    }
    __syncthreads();
    for (int c = tid; c <= NC; c += 256) {
        ws[WS_OFF + c] = off[c];
        if (c < NC) ws[WS_CURSOR + c] = off[c];
    }
}

// ---------------- scatter: token ids grouped by class ----------------
__global__ __launch_bounds__(256) void k_scatter(const int* __restrict__ target,
                                                 int* __restrict__ ws, int ntok) {
    const int n = blockIdx.x * 256 + threadIdx.x;
    if (n >= ntok) return;
    const int c = target[n] / NPC;
    const int pos = atomicAdd(&ws[WS_CURSOR + c], 1);
    ws[WS_ORDER + pos] = n;
}

// ---------------- phase 1: class softmax -> p1[n] ----------------
__global__ __launch_bounds__(256) void k_phase1(
    const float* __restrict__ x, const int* __restrict__ target,
    const float* __restrict__ W1, const float* __restrict__ b1,
    float* __restrict__ p1)
{
    __shared__ float xs[T1][D];   // 32 KB; logits stored back into cols [0,225)
    const int tid = threadIdx.x;
    const int n0  = blockIdx.x * T1;

    // stage 16 x-rows (2048 float4, 8 per thread)
    #pragma unroll
    for (int k = 0; k < 8; ++k) {
        int f = tid + k * 256;
        int row = f >> 7, col = f & 127;
        reinterpret_cast<float4*>(&xs[row][0])[col] =
            reinterpret_cast<const float4*>(x + (size_t)(n0 + row) * D)[col];
    }
    __syncthreads();

    float acc[T1];
    #pragma unroll
    for (int t = 0; t < T1; ++t) acc[t] = 0.f;

    const int c = tid;
    if (c < NC) {
        for (int d0 = 0; d0 < D; d0 += 4) {
            float w0 = W1[(d0 + 0) * NC + c];
            float w1 = W1[(d0 + 1) * NC + c];
            float w2 = W1[(d0 + 2) * NC + c];
            float w3 = W1[(d0 + 3) * NC + c];
            #pragma unroll
            for (int t = 0; t < T1; ++t) {
                float4 xv = *reinterpret_cast<const float4*>(&xs[t][d0]);
                acc[t] = fmaf(xv.x, w0, acc[t]);
                acc[t] = fmaf(xv.y, w1, acc[t]);
                acc[t] = fmaf(xv.z, w2, acc[t]);
                acc[t] = fmaf(xv.w, w3, acc[t]);
            }
        }
    }
    __syncthreads();           // all xs reads done
    if (c < NC) {
        const float bb = b1[c];
        #pragma unroll
        for (int t = 0; t < T1; ++t) xs[t][c] = acc[t] + bb;
    }
    __syncthreads();

    // per-wave softmax: wave w handles tokens w*4 .. w*4+3
    const int wv = tid >> 6, ln = tid & 63;
    for (int s = 0; s < 4; ++s) {
        const int t = wv * 4 + s;
        float v0 = xs[t][ln];
        float v1 = xs[t][64 + ln];
        float v2 = xs[t][128 + ln];
        float v3 = (192 + ln < NC) ? xs[t][192 + ln] : -INFINITY;
        float m = fmaxf(fmaxf(v0, v1), fmaxf(v2, v3));
        #pragma unroll
        for (int k = 32; k >= 1; k >>= 1) m = fmaxf(m, __shfl_xor(m, k, 64));
        float e = __expf(v0 - m) + __expf(v1 - m) + __expf(v2 - m) +
                  ((192 + ln < NC) ? __expf(v3 - m) : 0.f);
        #pragma unroll
        for (int k = 32; k >= 1; k >>= 1) e += __shfl_xor(e, k, 64);
        if (ln == 0) {
            const int cls = target[n0 + t] / NPC;
            p1[n0 + t] = __expf(xs[t][cls] - m) / e;
        }
    }
}

// ---------------- phase 2: per-class batched in-class softmax ----------------
__global__ __launch_bounds__(256) void k_phase2(
    const float* __restrict__ x, const int* __restrict__ target,
    const float* __restrict__ W2, const float* __restrict__ b2,
    const int* __restrict__ ws, const float* __restrict__ p1,
    float* __restrict__ out)
{
    __shared__ float xs[T2][D];   // 64 KB; logits reuse cols [0,224)
    __shared__ int stok[T2];
    const int tid   = threadIdx.x;
    const int c     = blockIdx.x;
    const int start = ws[WS_OFF + c];
    const int cnt   = ws[WS_OFF + c + 1] - start;
    if (cnt == 0) return;

    const float* W2c = W2 + (size_t)c * D * NPC;
    const float bb = (tid < NPC) ? b2[c * NPC + tid] : 0.f;

    for (int cb = 0; cb < cnt; cb += T2) {
        const int T = min(T2, cnt - cb);
        if (tid < T2) {
            int tt = min(tid, T - 1);                 // pad by duplicating last
            stok[tid] = ws[WS_ORDER + start + cb + tt];
        }
        __syncthreads();

        // stage 32 x-rows (4096 float4, 16 per thread)
        #pragma unroll
        for (int k = 0; k < 16; ++k) {
            int f = tid + k * 256;
            int row = f >> 7, col = f & 127;
            reinterpret_cast<float4*>(&xs[row][0])[col] =
                reinterpret_cast<const float4*>(x + (size_t)stok[row] * D)[col];
        }
        __syncthreads();

        float acc[T2];
        #pragma unroll
        for (int t = 0; t < T2; ++t) acc[t] = 0.f;

        if (tid < NPC) {
            for (int d0 = 0; d0 < D; d0 += 4) {
                float w0 = W2c[(d0 + 0) * NPC + tid];
                float w1 = W2c[(d0 + 1) * NPC + tid];
                float w2 = W2c[(d0 + 2) * NPC + tid];
                float w3 = W2c[(d0 + 3) * NPC + tid];
                #pragma unroll
                for (int t = 0; t < T2; ++t) {
                    float4 xv = *reinterpret_cast<const float4*>(&xs[t][d0]);
                    acc[t] = fmaf(xv.x, w0, acc[t]);
                    acc[t] = fmaf(xv.y, w1, acc[t]);
                    acc[t] = fmaf(xv.z, w2, acc[t]);
                    acc[t] = fmaf(xv.w, w3, acc[t]);
                }
            }
        }
        __syncthreads();          // all xs reads done
        if (tid < NPC) {
            #pragma unroll
            for (int t = 0; t < T2; ++t) xs[t][tid] = acc[t] + bb;
        }
        __syncthreads();

        // per-wave softmax: wave w handles tokens w*8 .. w*8+7
        const int wv = tid >> 6, ln = tid & 63;
        for (int s = 0; s < 8; ++s) {
            const int t = wv * 8 + s;
            float v0 = xs[t][ln];
            float v1 = xs[t][64 + ln];
            float v2 = xs[t][128 + ln];
            float v3 = (192 + ln < NPC) ? xs[t][192 + ln] : -INFINITY;
            float m = fmaxf(fmaxf(v0, v1), fmaxf(v2, v3));
            #pragma unroll
            for (int k = 32; k >= 1; k >>= 1) m = fmaxf(m, __shfl_xor(m, k, 64));
            float e = __expf(v0 - m) + __expf(v1 - m) + __expf(v2 - m) +
                      ((192 + ln < NPC) ? __expf(v3 - m) : 0.f);
            #pragma unroll
            for (int k = 32; k >= 1; k >>= 1) e += __shfl_xor(e, k, 64);
            if (ln == 0 && t < T) {
                const int tokid = stok[t];
                const int ii = target[tokid] % NPC;
                out[tokid] = p1[tokid] * (__expf(xs[t][ii] - m) / e);
            }
        }
        __syncthreads();          // before next chunk overwrites xs/stok
    }
}

extern "C" void kernel_launch(void* const* d_in, const int* in_sizes, int n_in,
                              void* d_out, int out_size, void* d_ws, size_t ws_size,
                              hipStream_t stream) {
    const float* x      = (const float*)d_in[0];
    const int*   target = (const int*)  d_in[1];
    const float* W1     = (const float*)d_in[2];
    const float* b1     = (const float*)d_in[3];
    const float* W2     = (const float*)d_in[4];
    const float* b2     = (const float*)d_in[5];
    float* out = (float*)d_out;
    int*   wsi = (int*)d_ws;
    float* p1  = (float*)d_ws + WS_P1;

    const int ntok = in_sizes[1];   // B*L = 4096

    k_prep   <<<1, 256, 0, stream>>>(target, wsi, ntok);
    k_scatter<<<(ntok + 255) / 256, 256, 0, stream>>>(target, wsi, ntok);
    k_phase1 <<<ntok / T1, 256, 0, stream>>>(x, target, W1, b1, p1);
    k_phase2 <<<NC, 256, 0, stream>>>(x, target, W2, b2, wsi, p1, out);
}

// Round 3
// 154.813 us; speedup vs baseline: 1.7022x; 1.2655x over previous
//
#include <hip/hip_runtime.h>
#include <cmath>

constexpr int D    = 512;
constexpr int NC   = 225;   // number of classes
constexpr int NCP  = 232;   // padded class count (mult of 8)
constexpr int NPC  = 224;   // outputs per class
constexpr int T2   = 16;    // tokens per block/chunk
constexpr int XPAD = 516;   // padded LDS row stride (floats)

// ws layout (int units):
constexpr int WS_OFF    = 0;        // 226 offsets
constexpr int WS_CURSOR = 256;      // 225 cursors
constexpr int WS_ORDER  = 512;      // 4096 token ids grouped by class
constexpr int WS_P1     = 4608;     // 4096 floats p1
constexpr int WS_NCHUNK = 8704;     // 1 int
constexpr int WS_CHUNK  = 8712;     // 3*481 ints (cls, start, cnt)
constexpr int WS_B1P    = 12288;    // 232 floats padded b1
constexpr int WS_W1P    = 16384;    // 512*232 floats padded W1

// ---------------- prep: histogram + scan + chunk table ----------------
__global__ __launch_bounds__(256) void k_prep(const int* __restrict__ target,
                                              int* __restrict__ ws, int ntok) {
    __shared__ int h[NC];
    const int tid = threadIdx.x;
    for (int c = tid; c < NC; c += 256) h[c] = 0;
    __syncthreads();
    for (int n = tid; n < ntok; n += 256) atomicAdd(&h[target[n] / NPC], 1);
    __syncthreads();
    if (tid == 0) {
        int s = 0, nch = 0;
        for (int c = 0; c < NC; ++c) {
            ws[WS_OFF + c] = s;
            ws[WS_CURSOR + c] = s;
            int cnt = h[c];
            for (int j = 0; j < cnt; j += T2) {
                ws[WS_CHUNK + nch * 3 + 0] = c;
                ws[WS_CHUNK + nch * 3 + 1] = s + j;
                ws[WS_CHUNK + nch * 3 + 2] = min(T2, cnt - j);
                ++nch;
            }
            s += cnt;
        }
        ws[WS_OFF + NC] = s;
        ws[WS_NCHUNK] = nch;
    }
}

// ---------------- aux: scatter (bid<16) + W1/b1 pad (bid>=16) ----------------
__global__ __launch_bounds__(256) void k_aux(const int* __restrict__ target,
                                             const float* __restrict__ W1,
                                             const float* __restrict__ b1,
                                             int* __restrict__ ws, int ntok) {
    const int tid = threadIdx.x, bid = blockIdx.x;
    if (bid < 16) {
        const int n = bid * 256 + tid;
        if (n < ntok) {
            const int c = target[n] / NPC;
            const int pos = atomicAdd(&ws[WS_CURSOR + c], 1);
            ws[WS_ORDER + pos] = n;
        }
    } else {
        float* W1p = (float*)ws + WS_W1P;
        float* b1p = (float*)ws + WS_B1P;
        const int idx = (bid - 16) * 256 + tid;
        if (idx < D * NCP) {
            const int d = idx / NCP, c = idx % NCP;
            W1p[idx] = (c < NC) ? W1[d * NC + c] : 0.f;
        }
        if (bid == 16 && tid < NCP) b1p[tid] = (tid < NC) ? b1[tid] : -1e30f;
    }
}

// ---------------- GEMM + softmax, templated on phase ----------------
// NP: padded output count (232 or 224). Tile: 8 outputs x 2 tokens / thread.
template <int NP, bool PHASE2>
__global__ __launch_bounds__(256) void k_gemm(
    const float* __restrict__ x, const int* __restrict__ target,
    const float* __restrict__ Wfull, const float* __restrict__ bfull,
    int* __restrict__ ws, float* __restrict__ p1, float* __restrict__ out)
{
    constexpr int NOG = NP / 8;
    constexpr int NTH = NOG * 8;
    __shared__ float xs[T2][XPAD];
    __shared__ int stok[T2];

    const int tid = threadIdx.x, bid = blockIdx.x;

    const float* wptr;
    const float* bptr;
    int cnt;
    if (PHASE2) {
        const int nch = ws[WS_NCHUNK];
        if (bid >= nch) return;
        const int cls   = ws[WS_CHUNK + bid * 3 + 0];
        const int start = ws[WS_CHUNK + bid * 3 + 1];
        cnt             = ws[WS_CHUNK + bid * 3 + 2];
        if (tid < T2) stok[tid] = ws[WS_ORDER + start + min(tid, cnt - 1)];
        wptr = Wfull + (size_t)cls * D * NP;
        bptr = bfull + cls * NP;
    } else {
        cnt = T2;
        if (tid < T2) stok[tid] = bid * T2 + tid;
        wptr = Wfull;   // padded W1 in ws
        bptr = bfull;   // padded b1 in ws
    }
    __syncthreads();

    // stage T2 x-rows, coalesced float4, padded rows
    #pragma unroll
    for (int k = 0; k < (T2 * 128) / 256; ++k) {
        const int f = tid + k * 256;
        const int row = f >> 7, col = f & 127;
        *reinterpret_cast<float4*>(&xs[row][col * 4]) =
            reinterpret_cast<const float4*>(x + (size_t)stok[row] * D)[col];
    }
    __syncthreads();

    const int og = tid % NOG;        // output group (8 outputs)
    const int tg = tid / NOG;        // token group (2 tokens)
    const bool active = tid < NTH;
    const int t0 = tg * 2;

    float acc[8][2];
    #pragma unroll
    for (int j = 0; j < 8; ++j) { acc[j][0] = 0.f; acc[j][1] = 0.f; }

    if (active) {
        const float* wrow = wptr + og * 8;
        #pragma unroll 2
        for (int d0 = 0; d0 < D; d0 += 4) {
            float4 xa4 = *reinterpret_cast<const float4*>(&xs[t0][d0]);
            float4 xb4 = *reinterpret_cast<const float4*>(&xs[t0 + 1][d0]);
            const float* xa = &xa4.x;
            const float* xb = &xb4.x;
            #pragma unroll
            for (int k = 0; k < 4; ++k) {
                float4 wlo = *reinterpret_cast<const float4*>(wrow + (size_t)(d0 + k) * NP);
                float4 whi = *reinterpret_cast<const float4*>(wrow + (size_t)(d0 + k) * NP + 4);
                const float* wl = &wlo.x;
                const float* wh = &whi.x;
                #pragma unroll
                for (int j = 0; j < 4; ++j) {
                    acc[j][0]     = fmaf(xa[k], wl[j], acc[j][0]);
                    acc[j][1]     = fmaf(xb[k], wl[j], acc[j][1]);
                    acc[j + 4][0] = fmaf(xa[k], wh[j], acc[j + 4][0]);
                    acc[j + 4][1] = fmaf(xb[k], wh[j], acc[j + 4][1]);
                }
            }
        }
    }
    __syncthreads();   // all xs reads done

    if (active) {
        float4 blo = *reinterpret_cast<const float4*>(bptr + og * 8);
        float4 bhi = *reinterpret_cast<const float4*>(bptr + og * 8 + 4);
        const float* bl = &blo.x;
        const float* bh = &bhi.x;
        #pragma unroll
        for (int i = 0; i < 2; ++i) {
            float4 lo, hi;
            lo.x = acc[0][i] + bl[0]; lo.y = acc[1][i] + bl[1];
            lo.z = acc[2][i] + bl[2]; lo.w = acc[3][i] + bl[3];
            hi.x = acc[4][i] + bh[0]; hi.y = acc[5][i] + bh[1];
            hi.z = acc[6][i] + bh[2]; hi.w = acc[7][i] + bh[3];
            *reinterpret_cast<float4*>(&xs[t0 + i][og * 8])     = lo;
            *reinterpret_cast<float4*>(&xs[t0 + i][og * 8 + 4]) = hi;
        }
    }
    __syncthreads();

    // softmax: wave wv handles tokens wv*4 .. wv*4+3
    const int wv = tid >> 6, ln = tid & 63;
    #pragma unroll
    for (int s = 0; s < 4; ++s) {
        const int t = wv * 4 + s;
        float v0 = xs[t][ln];
        float v1 = xs[t][64 + ln];
        float v2 = xs[t][128 + ln];
        float v3 = (192 + ln < NP) ? xs[t][192 + ln] : -1e30f;
        float m = fmaxf(fmaxf(v0, v1), fmaxf(v2, v3));
        #pragma unroll
        for (int k = 32; k >= 1; k >>= 1) m = fmaxf(m, __shfl_xor(m, k, 64));
        float e = __expf(v0 - m) + __expf(v1 - m) + __expf(v2 - m) +
                  ((192 + ln < NP) ? __expf(v3 - m) : 0.f);
        #pragma unroll
        for (int k = 32; k >= 1; k >>= 1) e += __shfl_xor(e, k, 64);
        if (ln == 0 && t < cnt) {
            const int tokid = stok[t];
            if (PHASE2) {
                const int ii = target[tokid] % NPC;
                out[tokid] = p1[tokid] * (__expf(xs[t][ii] - m) / e);
            } else {
                const int cls = target[tokid] / NPC;
                p1[tokid] = __expf(xs[t][cls] - m) / e;
            }
        }
    }
}

extern "C" void kernel_launch(void* const* d_in, const int* in_sizes, int n_in,
                              void* d_out, int out_size, void* d_ws, size_t ws_size,
                              hipStream_t stream) {
    const float* x      = (const float*)d_in[0];
    const int*   target = (const int*)  d_in[1];
    const float* W1     = (const float*)d_in[2];
    const float* b1     = (const float*)d_in[3];
    const float* W2     = (const float*)d_in[4];
    const float* b2     = (const float*)d_in[5];
    float* out = (float*)d_out;
    int*   wsi = (int*)d_ws;
    float* p1  = (float*)d_ws + WS_P1;
    float* W1p = (float*)d_ws + WS_W1P;
    float* b1p = (float*)d_ws + WS_B1P;

    const int ntok = in_sizes[1];               // 4096
    const int maxchunks = ntok / T2 + NC;       // 481 upper bound

    k_prep<<<1, 256, 0, stream>>>(target, wsi, ntok);
    k_aux <<<16 + (D * NCP + 255) / 256, 256, 0, stream>>>(target, W1, b1, wsi, ntok);
    k_gemm<NCP, false><<<ntok / T2, 256, 0, stream>>>(x, target, W1p, b1p, wsi, p1, out);
    k_gemm<NPC, true ><<<maxchunks, 256, 0, stream>>>(x, target, W2,  b2,  wsi, p1, out);
}

// Round 4
// 83.437 us; speedup vs baseline: 3.1583x; 1.8555x over previous
//
#include <hip/hip_runtime.h>
#include <cmath>

constexpr int D    = 512;
constexpr int NC   = 225;   // classes
constexpr int NCP  = 232;   // padded classes (mult of 8)
constexpr int NPC  = 224;   // outputs per class
constexpr int TB   = 16;    // tokens per chunk
constexpr int XPAD = 516;   // x LDS row stride
constexpr int LSP  = 236;   // logits LDS row stride

// ws layout (int units)
constexpr int WS_NCHUNK = 0;        // 1
constexpr int WS_ORDER  = 256;      // 4096 token ids grouped by class
constexpr int WS_CHUNK  = 4608;     // 737 * 4 ints (cls,start,cnt,pad); 16B aligned
constexpr int WS_P1     = 7680;     // 4096 floats
constexpr int WS_P2     = 11776;    // 4096 floats
constexpr int WS_B1P    = 15872;    // 232 floats padded b1
constexpr int WS_W1P    = 16384;    // 512*232 floats padded W1

// ---------- prep: histogram + scans + chunk table + scatter (one block) ----------
__global__ __launch_bounds__(256) void k_prep(const int* __restrict__ target,
                                              int* __restrict__ ws, int ntok) {
    __shared__ int h[256];
    __shared__ int sc[256];
    __shared__ int sc2[256];
    __shared__ int cur[NC];
    const int tid = threadIdx.x;
    h[tid] = 0;
    __syncthreads();
    for (int n = tid; n < ntok; n += 256) atomicAdd(&h[target[n] / NPC], 1);
    __syncthreads();
    const int hv = h[tid];
    // inclusive scan of h -> sc
    sc[tid] = hv; __syncthreads();
    for (int o = 1; o < 256; o <<= 1) {
        int add = (tid >= o) ? sc[tid - o] : 0;
        __syncthreads();
        sc[tid] += add;
        __syncthreads();
    }
    const int start = sc[tid] - hv;               // exclusive offset
    const int nch = (tid < NC) ? (hv + TB - 1) / TB : 0;
    sc2[tid] = nch; __syncthreads();
    for (int o = 1; o < 256; o <<= 1) {
        int add = (tid >= o) ? sc2[tid - o] : 0;
        __syncthreads();
        sc2[tid] += add;
        __syncthreads();
    }
    const int P1C = ntok / TB;                    // phase-1 chunk count
    if (tid < NC) {
        cur[tid] = start;
        const int cb = P1C + sc2[tid] - nch;
        for (int j = 0; j < nch; ++j) {
            const int e = WS_CHUNK + (cb + j) * 4;
            ws[e + 0] = tid;
            ws[e + 1] = start + j * TB;
            ws[e + 2] = min(TB, hv - j * TB);
            ws[e + 3] = 0;
        }
    }
    if (tid < P1C) {                              // phase-1 entries 0..P1C-1
        const int e = WS_CHUNK + tid * 4;
        ws[e + 0] = -1;
        ws[e + 1] = tid * TB;
        ws[e + 2] = TB;
        ws[e + 3] = 0;
    }
    if (tid == 255) ws[WS_NCHUNK] = P1C + sc2[255];
    __syncthreads();
    // scatter (LDS cursors)
    for (int n = tid; n < ntok; n += 256) {
        const int c = target[n] / NPC;
        const int pos = atomicAdd(&cur[c], 1);
        ws[WS_ORDER + pos] = n;
    }
}

// ---------- pad W1 (512x225 -> 512x232) and b1 into ws ----------
__global__ __launch_bounds__(256) void k_pad(const float* __restrict__ W1,
                                             const float* __restrict__ b1,
                                             int* __restrict__ ws) {
    float* W1p = (float*)ws + WS_W1P;
    float* b1p = (float*)ws + WS_B1P;
    const int idx = blockIdx.x * 256 + threadIdx.x;
    if (idx < D * NCP) {
        const int d = idx / NCP, c = idx % NCP;
        W1p[idx] = (c < NC) ? W1[d * NC + c] : 0.f;
    }
    if (blockIdx.x == 0 && threadIdx.x < NCP)
        b1p[threadIdx.x] = (threadIdx.x < NC) ? b1[threadIdx.x] : -1e30f;
}

// ---------- main: unified chunk GEMM + softmax ----------
// 256 threads. K-split: half 0 -> d[0,256), half 1 -> d[256,512).
// Per half: og in [0,NOG), tg in [0,4): tile 8 outputs x 4 tokens.
__global__ __launch_bounds__(256) void k_main(
    const float* __restrict__ x, const int* __restrict__ target,
    const float* __restrict__ W2, const float* __restrict__ b2,
    int* __restrict__ ws)
{
    __shared__ float xs[TB][XPAD];
    __shared__ float ls[TB][LSP];
    __shared__ int stok[TB];

    const int tid = threadIdx.x, bid = blockIdx.x;
    if (bid >= ws[WS_NCHUNK]) return;

    const int4 ce = *reinterpret_cast<const int4*>(ws + WS_CHUNK + bid * 4);
    const int cls = ce.x, start = ce.y, cnt = ce.z;
    const bool ph2 = (cls >= 0);
    const int NP  = ph2 ? NPC : NCP;
    const int NOG = ph2 ? 28 : 29;
    const float* wbase = ph2 ? (W2 + (size_t)cls * D * NPC)
                             : ((const float*)ws + WS_W1P);
    const float* bptr  = ph2 ? (b2 + cls * NPC)
                             : ((const float*)ws + WS_B1P);
    float* p1 = (float*)ws + WS_P1;
    float* p2 = (float*)ws + WS_P2;

    if (tid < TB)
        stok[tid] = ph2 ? ws[WS_ORDER + start + min(tid, cnt - 1)] : (start + tid);
    __syncthreads();

    // stage 16 x rows (coalesced float4)
    #pragma unroll
    for (int k = 0; k < 8; ++k) {
        const int f = tid + k * 256;
        const int row = f >> 7, col = f & 127;
        *reinterpret_cast<float4*>(&xs[row][col * 4]) =
            reinterpret_cast<const float4*>(x + (size_t)stok[row] * D)[col];
    }
    __syncthreads();

    const int half = tid >> 7;
    const int ht   = tid & 127;
    const int og   = ht % NOG;
    const int tg   = ht / NOG;
    const bool active = (tg < 4);
    const int t0 = tg * 4;
    const int kbase = half * 256;

    float acc[8][4];
    #pragma unroll
    for (int j = 0; j < 8; ++j)
        #pragma unroll
        for (int i = 0; i < 4; ++i) acc[j][i] = 0.f;

    if (active) {
        const float* wp = wbase + (size_t)kbase * NP + og * 8;
        float4 wl0[4], wh0[4], wl1[4], wh1[4], xa[4], xb[4];

        #pragma unroll
        for (int k = 0; k < 4; ++k) {
            wl0[k] = *reinterpret_cast<const float4*>(wp + (size_t)k * NP);
            wh0[k] = *reinterpret_cast<const float4*>(wp + (size_t)k * NP + 4);
        }
        #pragma unroll
        for (int i = 0; i < 4; ++i)
            xa[i] = *reinterpret_cast<const float4*>(&xs[t0 + i][kbase]);

        for (int d0 = 0; d0 < 256; d0 += 8) {
            // prefetch group B (d0+4)
            #pragma unroll
            for (int k = 0; k < 4; ++k) {
                wl1[k] = *reinterpret_cast<const float4*>(wp + (size_t)(k + 4) * NP);
                wh1[k] = *reinterpret_cast<const float4*>(wp + (size_t)(k + 4) * NP + 4);
            }
            #pragma unroll
            for (int i = 0; i < 4; ++i)
                xb[i] = *reinterpret_cast<const float4*>(&xs[t0 + i][kbase + d0 + 4]);

            // FMA group A (d0..d0+3)
            #pragma unroll
            for (int k = 0; k < 4; ++k) {
                #pragma unroll
                for (int i = 0; i < 4; ++i) {
                    const float xk = (&xa[i].x)[k];
                    acc[0][i] = fmaf(xk, wl0[k].x, acc[0][i]);
                    acc[1][i] = fmaf(xk, wl0[k].y, acc[1][i]);
                    acc[2][i] = fmaf(xk, wl0[k].z, acc[2][i]);
                    acc[3][i] = fmaf(xk, wl0[k].w, acc[3][i]);
                    acc[4][i] = fmaf(xk, wh0[k].x, acc[4][i]);
                    acc[5][i] = fmaf(xk, wh0[k].y, acc[5][i]);
                    acc[6][i] = fmaf(xk, wh0[k].z, acc[6][i]);
                    acc[7][i] = fmaf(xk, wh0[k].w, acc[7][i]);
                }
            }
            // prefetch group A of next macro-iter (d0+8)
            if (d0 + 8 < 256) {
                #pragma unroll
                for (int k = 0; k < 4; ++k) {
                    wl0[k] = *reinterpret_cast<const float4*>(wp + (size_t)(k + 8) * NP);
                    wh0[k] = *reinterpret_cast<const float4*>(wp + (size_t)(k + 8) * NP + 4);
                }
                #pragma unroll
                for (int i = 0; i < 4; ++i)
                    xa[i] = *reinterpret_cast<const float4*>(&xs[t0 + i][kbase + d0 + 8]);
            }
            // FMA group B (d0+4..d0+7)
            #pragma unroll
            for (int k = 0; k < 4; ++k) {
                #pragma unroll
                for (int i = 0; i < 4; ++i) {
                    const float xk = (&xb[i].x)[k];
                    acc[0][i] = fmaf(xk, wl1[k].x, acc[0][i]);
                    acc[1][i] = fmaf(xk, wl1[k].y, acc[1][i]);
                    acc[2][i] = fmaf(xk, wl1[k].z, acc[2][i]);
                    acc[3][i] = fmaf(xk, wl1[k].w, acc[3][i]);
                    acc[4][i] = fmaf(xk, wh1[k].x, acc[4][i]);
                    acc[5][i] = fmaf(xk, wh1[k].y, acc[5][i]);
                    acc[6][i] = fmaf(xk, wh1[k].z, acc[6][i]);
                    acc[7][i] = fmaf(xk, wh1[k].w, acc[7][i]);
                }
            }
            wp += 8 * NP;
        }
    }

    // epilogue: half 0 writes logits+bias; half 1 accumulates
    float4 bl = {0, 0, 0, 0}, bh = {0, 0, 0, 0};
    if (active && half == 0) {
        bl = *reinterpret_cast<const float4*>(bptr + og * 8);
        bh = *reinterpret_cast<const float4*>(bptr + og * 8 + 4);
        #pragma unroll
        for (int i = 0; i < 4; ++i) {
            float4 lo = {acc[0][i] + bl.x, acc[1][i] + bl.y, acc[2][i] + bl.z, acc[3][i] + bl.w};
            float4 hi = {acc[4][i] + bh.x, acc[5][i] + bh.y, acc[6][i] + bh.z, acc[7][i] + bh.w};
            *reinterpret_cast<float4*>(&ls[t0 + i][og * 8])     = lo;
            *reinterpret_cast<float4*>(&ls[t0 + i][og * 8 + 4]) = hi;
        }
    }
    __syncthreads();
    if (active && half == 1) {
        #pragma unroll
        for (int i = 0; i < 4; ++i) {
            float4 lo = *reinterpret_cast<float4*>(&ls[t0 + i][og * 8]);
            float4 hi = *reinterpret_cast<float4*>(&ls[t0 + i][og * 8 + 4]);
            lo.x += acc[0][i]; lo.y += acc[1][i]; lo.z += acc[2][i]; lo.w += acc[3][i];
            hi.x += acc[4][i]; hi.y += acc[5][i]; hi.z += acc[6][i]; hi.w += acc[7][i];
            *reinterpret_cast<float4*>(&ls[t0 + i][og * 8])     = lo;
            *reinterpret_cast<float4*>(&ls[t0 + i][og * 8 + 4]) = hi;
        }
    }
    __syncthreads();

    // softmax: wave wv handles tokens wv*4 .. wv*4+3
    const int wv = tid >> 6, ln = tid & 63;
    #pragma unroll
    for (int s = 0; s < 4; ++s) {
        const int t = wv * 4 + s;
        float v0 = ls[t][ln];
        float v1 = ls[t][64 + ln];
        float v2 = ls[t][128 + ln];
        float v3 = (192 + ln < NP) ? ls[t][192 + ln] : -1e30f;
        float m = fmaxf(fmaxf(v0, v1), fmaxf(v2, v3));
        #pragma unroll
        for (int k = 32; k >= 1; k >>= 1) m = fmaxf(m, __shfl_xor(m, k, 64));
        float e = __expf(v0 - m) + __expf(v1 - m) + __expf(v2 - m) +
                  ((192 + ln < NP) ? __expf(v3 - m) : 0.f);
        #pragma unroll
        for (int k = 32; k >= 1; k >>= 1) e += __shfl_xor(e, k, 64);
        if (ln == 0 && t < cnt) {
            const int tok = stok[t];
            const int tt  = target[tok];
            const int col = ph2 ? (tt % NPC) : (tt / NPC);
            const float p = __expf(ls[t][col] - m) / e;
            (ph2 ? p2 : p1)[tok] = p;
        }
    }
}

// ---------- combine: out = p1 * p2 ----------
__global__ __launch_bounds__(256) void k_combine(const int* __restrict__ ws,
                                                 float* __restrict__ out, int ntok) {
    const int n = blockIdx.x * 256 + threadIdx.x;
    const float* p1 = (const float*)ws + WS_P1;
    const float* p2 = (const float*)ws + WS_P2;
    if (n < ntok) out[n] = p1[n] * p2[n];
}

extern "C" void kernel_launch(void* const* d_in, const int* in_sizes, int n_in,
                              void* d_out, int out_size, void* d_ws, size_t ws_size,
                              hipStream_t stream) {
    const float* x      = (const float*)d_in[0];
    const int*   target = (const int*)  d_in[1];
    const float* W1     = (const float*)d_in[2];
    const float* b1     = (const float*)d_in[3];
    const float* W2     = (const float*)d_in[4];
    const float* b2     = (const float*)d_in[5];
    float* out = (float*)d_out;
    int*   wsi = (int*)d_ws;

    const int ntok = in_sizes[1];                       // 4096
    const int maxgrid = ntok / TB + (ntok / TB + NC);   // 737

    k_prep   <<<1, 256, 0, stream>>>(target, wsi, ntok);
    k_pad    <<<(D * NCP + 255) / 256, 256, 0, stream>>>(W1, b1, wsi);
    k_main   <<<maxgrid, 256, 0, stream>>>(x, target, W2, b2, wsi);
    k_combine<<<(ntok + 255) / 256, 256, 0, stream>>>(wsi, out, ntok);
}